// Round 2
// baseline (42.204 us; speedup 1.0000x reference)
//
#include <hip/hip_runtime.h>

#define K       256
#define NEDGE   257
#define NPTS    76800            // 240*320
#define THREADS 256
#define CPB     (NPTS / THREADS) // 300 chunks per batch
#define NB      (2 * CPB)        // 600 blocks total

// ws layout (bytes):
//   [0,4)        uint counter        — memset 0xFF each call (wrap trick)
//   [4,2052)     uint minSlots[512]  — memset 0xFF each call (= +inf for uint-min of f32 bits)
//   [2112,...)   float partials[NB]  — written every call before read; no init needed

__global__ __launch_bounds__(THREADS)
void chamfer_fused(const float* __restrict__ target,
                   const float* __restrict__ edges,
                   unsigned int* __restrict__ counter,
                   unsigned int* __restrict__ minSlots,
                   float* __restrict__ partials,
                   float* __restrict__ out) {
    __shared__ float sC[K];
    __shared__ float sP[THREADS];
    __shared__ float sRed[THREADS];
    __shared__ int   sIsLast;

    const int t     = threadIdx.x;
    const int b     = blockIdx.x / CPB;
    const int chunk = blockIdx.x % CPB;

    // centers from edges (K == THREADS)
    {
        const float* e = edges + b * NEDGE;
        sC[t] = 0.5f * (e[t] + e[t + 1]);
    }
    sP[t] = target[(size_t)b * NPTS + (size_t)chunk * THREADS + t];
    __syncthreads();

    // ---- Pass 1: this thread's point vs all 256 centers (4 independent chains) ----
    const float d = sP[t];
    float m0 = 1e30f, m1 = 1e30f, m2 = 1e30f, m3 = 1e30f;
    const float4* c4 = (const float4*)sC;   // uniform address -> LDS broadcast, no conflicts
    #pragma unroll 16
    for (int i = 0; i < K / 4; ++i) {
        const float4 c = c4[i];
        float x;
        x = d - c.x; m0 = fminf(m0, x * x);
        x = d - c.y; m1 = fminf(m1, x * x);
        x = d - c.z; m2 = fminf(m2, x * x);
        x = d - c.w; m3 = fminf(m3, x * x);
    }
    const float pmin = fminf(fminf(m0, m1), fminf(m2, m3));

    // ---- Pass 2: this thread's center vs the block's 256 points ----
    const float c = sC[t];
    float r0 = 1e30f, r1 = 1e30f, r2 = 1e30f, r3 = 1e30f;
    const float4* p4 = (const float4*)sP;
    #pragma unroll 16
    for (int i = 0; i < THREADS / 4; ++i) {
        const float4 p = p4[i];
        float x;
        x = c - p.x; r0 = fminf(r0, x * x);
        x = c - p.y; r1 = fminf(r1, x * x);
        x = c - p.z; r2 = fminf(r2, x * x);
        x = c - p.w; r3 = fminf(r3, x * x);
    }
    const float rm = fminf(fminf(r0, r1), fminf(r2, r3));
    // uint compare == float compare for non-negative floats; min is order-independent
    atomicMin(&minSlots[b * K + t], __float_as_uint(rm));   // device scope by default

    // ---- deterministic block-sum of pass-1 mins ----
    sRed[t] = pmin;
    __syncthreads();
    for (int s = THREADS / 2; s > 0; s >>= 1) {
        if (t < s) sRed[t] += sRed[t + s];
        __syncthreads();
    }
    if (t == 0) partials[blockIdx.x] = sRed[0];

    // ---- completion: counter starts at 0xFFFFFFFF (memset 0xFF); wraps on 1st add.
    // Old values observed across NB adds: 0xFFFFFFFF, 0, 1, ..., NB-2.
    // Exactly one block observes NB-2 -> it is last.
    if (t == 0) {
        __threadfence();  // release all prior global writes (device scope)
        unsigned int old = __hip_atomic_fetch_add(counter, 1u, __ATOMIC_ACQ_REL,
                                                  __HIP_MEMORY_SCOPE_AGENT);
        sIsLast = (old == (unsigned int)(NB - 2));
    }
    __syncthreads();
    if (!sIsLast) return;
    __threadfence();  // acquire side: invalidate stale cached lines

    // ---- last block: final reduction (fixed order -> deterministic) ----
    float s = __uint_as_float(__hip_atomic_load(&minSlots[t], __ATOMIC_RELAXED,
                                                __HIP_MEMORY_SCOPE_AGENT))
            + __uint_as_float(__hip_atomic_load(&minSlots[t + THREADS], __ATOMIC_RELAXED,
                                                __HIP_MEMORY_SCOPE_AGENT));
    for (int i = t; i < NB; i += THREADS)
        s += __hip_atomic_load(&partials[i], __ATOMIC_RELAXED, __HIP_MEMORY_SCOPE_AGENT);

    sRed[t] = s;
    __syncthreads();
    for (int st = THREADS / 2; st > 0; st >>= 1) {
        if (t < st) sRed[t] += sRed[t + st];
        __syncthreads();
    }
    if (t == 0) out[0] = sRed[0] * 0.5f;   // mean over B=2
}

extern "C" void kernel_launch(void* const* d_in, const int* in_sizes, int n_in,
                              void* d_out, int out_size, void* d_ws, size_t ws_size,
                              hipStream_t stream) {
    const float* target = (const float*)d_in[0];   // [2,1,240,320] fp32
    const float* edges  = (const float*)d_in[1];   // [2,257] fp32
    float* out = (float*)d_out;

    unsigned int* counter  = (unsigned int*)d_ws;
    unsigned int* minSlots = counter + 1;                          // 512 uints
    float*        partials = (float*)((char*)d_ws + 2112);         // NB floats

    // init counter (wrap trick) + minSlots (+inf for uint-min) in one node
    hipMemsetAsync(d_ws, 0xFF, 4 + 2 * K * sizeof(unsigned int), stream);
    chamfer_fused<<<NB, THREADS, 0, stream>>>(target, edges, counter, minSlots,
                                              partials, out);
}

// Round 3
// 39.889 us; speedup vs baseline: 1.0580x; 1.0580x over previous
//
#include <hip/hip_runtime.h>

#define K       256
#define NEDGE   257
#define NPTS    76800            // 240*320
#define THREADS 256
#define CPB     (NPTS / THREADS) // 300 chunks per batch
#define NB      (2 * CPB)        // 600 blocks total

// ws layout:
//   uint counter            [0]       — init kernel sets 0
//   uint minSlots[512]      [1..512]  — init kernel sets +inf bits
//   float partials[NB]      @ byte 2112 — written before read each call

__global__ void chamfer_init(unsigned int* __restrict__ ws) {
    const int t = threadIdx.x;
    if (t == 0) ws[0] = 0u;                       // counter
    ws[1 + t] = 0x7F800000u;                      // +inf
    ws[1 + t + THREADS] = 0x7F800000u;
}

__global__ __launch_bounds__(THREADS)
void chamfer_fused(const float* __restrict__ target,
                   const float* __restrict__ edges,
                   unsigned int* __restrict__ counter,
                   unsigned int* __restrict__ minSlots,
                   float* __restrict__ partials,
                   float* __restrict__ out) {
    __shared__ float sC[K];
    __shared__ float sP[THREADS];
    __shared__ float sRed[THREADS];
    __shared__ int   sIsLast;

    const int t     = threadIdx.x;
    const int b     = blockIdx.x / CPB;
    const int chunk = blockIdx.x % CPB;

    // centers from edges (K == THREADS)
    {
        const float* e = edges + b * NEDGE;
        sC[t] = 0.5f * (e[t] + e[t + 1]);
    }
    sP[t] = target[(size_t)b * NPTS + (size_t)chunk * THREADS + t];
    __syncthreads();

    // ---- Pass 1: this thread's point vs all 256 centers (4 independent chains) ----
    const float d = sP[t];
    float m0 = 1e30f, m1 = 1e30f, m2 = 1e30f, m3 = 1e30f;
    const float4* c4 = (const float4*)sC;   // uniform address -> LDS broadcast
    #pragma unroll 16
    for (int i = 0; i < K / 4; ++i) {
        const float4 c = c4[i];
        float x;
        x = d - c.x; m0 = fminf(m0, x * x);
        x = d - c.y; m1 = fminf(m1, x * x);
        x = d - c.z; m2 = fminf(m2, x * x);
        x = d - c.w; m3 = fminf(m3, x * x);
    }
    const float pmin = fminf(fminf(m0, m1), fminf(m2, m3));

    // ---- Pass 2: this thread's center vs the block's 256 points ----
    const float c = sC[t];
    float r0 = 1e30f, r1 = 1e30f, r2 = 1e30f, r3 = 1e30f;
    const float4* p4 = (const float4*)sP;
    #pragma unroll 16
    for (int i = 0; i < THREADS / 4; ++i) {
        const float4 p = p4[i];
        float x;
        x = c - p.x; r0 = fminf(r0, x * x);
        x = c - p.y; r1 = fminf(r1, x * x);
        x = c - p.z; r2 = fminf(r2, x * x);
        x = c - p.w; r3 = fminf(r3, x * x);
    }
    const float rm = fminf(fminf(r0, r1), fminf(r2, r3));
    // uint compare == float compare for non-negative floats; min is order-independent
    atomicMin(&minSlots[b * K + t], __float_as_uint(rm));

    // ---- deterministic block-sum of pass-1 mins ----
    sRed[t] = pmin;
    __syncthreads();
    for (int s = THREADS / 2; s > 0; s >>= 1) {
        if (t < s) sRed[t] += sRed[t + s];
        __syncthreads();
    }
    if (t == 0) partials[blockIdx.x] = sRed[0];

    // ---- last-block detection (counter starts at 0) ----
    if (t == 0) {
        __threadfence();  // release prior global writes (device scope)
        unsigned int old = __hip_atomic_fetch_add(counter, 1u, __ATOMIC_ACQ_REL,
                                                  __HIP_MEMORY_SCOPE_AGENT);
        sIsLast = (old == (unsigned int)(NB - 1));
    }
    __syncthreads();
    if (!sIsLast) return;
    __threadfence();  // acquire: see all blocks' writes

    // ---- last block: final reduction (fixed order -> deterministic) ----
    float s = __uint_as_float(__hip_atomic_load(&minSlots[t], __ATOMIC_RELAXED,
                                                __HIP_MEMORY_SCOPE_AGENT))
            + __uint_as_float(__hip_atomic_load(&minSlots[t + THREADS], __ATOMIC_RELAXED,
                                                __HIP_MEMORY_SCOPE_AGENT));
    for (int i = t; i < NB; i += THREADS)
        s += __hip_atomic_load(&partials[i], __ATOMIC_RELAXED, __HIP_MEMORY_SCOPE_AGENT);

    sRed[t] = s;
    __syncthreads();
    for (int st = THREADS / 2; st > 0; st >>= 1) {
        if (t < st) sRed[t] += sRed[t + st];
        __syncthreads();
    }
    if (t == 0) out[0] = sRed[0] * 0.5f;   // mean over B=2
}

extern "C" void kernel_launch(void* const* d_in, const int* in_sizes, int n_in,
                              void* d_out, int out_size, void* d_ws, size_t ws_size,
                              hipStream_t stream) {
    const float* target = (const float*)d_in[0];   // [2,1,240,320] fp32
    const float* edges  = (const float*)d_in[1];   // [2,257] fp32
    float* out = (float*)d_out;

    unsigned int* counter  = (unsigned int*)d_ws;
    unsigned int* minSlots = counter + 1;                   // 512 uints
    float*        partials = (float*)((char*)d_ws + 2112);  // NB floats

    chamfer_init<<<1, THREADS, 0, stream>>>((unsigned int*)d_ws);
    chamfer_fused<<<NB, THREADS, 0, stream>>>(target, edges, counter, minSlots,
                                              partials, out);
}

// Round 4
// 32.517 us; speedup vs baseline: 1.2979x; 1.2267x over previous
//
#include <hip/hip_runtime.h>

#define K        256
#define NEDGE    257
#define NPTS     76800              // 240*320
#define THREADS  256
#define PPB      512                // points per A-block
#define CHUNKS   (NPTS / PPB)       // 150 per batch
#define NBA      (2 * CHUNKS)       // 300 A-blocks
#define BTHREADS 1024

// ws layout (no init required — everything is written before it is read, every call):
//   float partials[NBA]                  @ byte 0      (dist2 per-block sums)
//   float blockMins[2][CHUNKS][K]        @ byte 2048   (per-block per-center mins)

__global__ __launch_bounds__(THREADS)
void chamfer_a(const float* __restrict__ target,
               const float* __restrict__ edges,
               float* __restrict__ partials,
               float* __restrict__ blockMins) {
    __shared__ float sC[K];
    __shared__ float sP[PPB];
    __shared__ float sRed[THREADS];

    const int t     = threadIdx.x;
    const int b     = blockIdx.x / CHUNKS;
    const int chunk = blockIdx.x % CHUNKS;

    // centers from edges (K == THREADS)
    {
        const float* e = edges + b * NEDGE;
        sC[t] = 0.5f * (e[t] + e[t + 1]);
    }
    {
        const float* tp = target + (size_t)b * NPTS + (size_t)chunk * PPB;
        sP[t]       = tp[t];
        sP[t + 256] = tp[t + 256];
    }
    __syncthreads();

    // ---- Pass 1: points t and t+256 vs all 256 centers (4 independent chains) ----
    const float d0 = sP[t], d1 = sP[t + 256];
    float a0 = 1e30f, a1 = 1e30f, b0 = 1e30f, b1 = 1e30f;
    const float4* c4 = (const float4*)sC;   // uniform address -> LDS broadcast
    #pragma unroll 16
    for (int i = 0; i < K / 4; ++i) {
        const float4 c = c4[i];
        float x;
        x = d0 - c.x; a0 = fminf(a0, x * x);
        x = d0 - c.y; a1 = fminf(a1, x * x);
        x = d0 - c.z; a0 = fminf(a0, x * x);
        x = d0 - c.w; a1 = fminf(a1, x * x);
        x = d1 - c.x; b0 = fminf(b0, x * x);
        x = d1 - c.y; b1 = fminf(b1, x * x);
        x = d1 - c.z; b0 = fminf(b0, x * x);
        x = d1 - c.w; b1 = fminf(b1, x * x);
    }
    const float psum = fminf(a0, a1) + fminf(b0, b1);

    // ---- Pass 2: center t vs the block's 512 points ----
    const float c = sC[t];
    float r0 = 1e30f, r1 = 1e30f, r2 = 1e30f, r3 = 1e30f;
    const float4* p4 = (const float4*)sP;
    #pragma unroll 16
    for (int i = 0; i < PPB / 4; ++i) {
        const float4 p = p4[i];
        float x;
        x = c - p.x; r0 = fminf(r0, x * x);
        x = c - p.y; r1 = fminf(r1, x * x);
        x = c - p.z; r2 = fminf(r2, x * x);
        x = c - p.w; r3 = fminf(r3, x * x);
    }
    // coalesced plain store — no atomics
    blockMins[((size_t)b * CHUNKS + chunk) * K + t] = fminf(fminf(r0, r1), fminf(r2, r3));

    // ---- deterministic block-sum of pass-1 mins ----
    sRed[t] = psum;
    __syncthreads();
    for (int s = THREADS / 2; s > 0; s >>= 1) {
        if (t < s) sRed[t] += sRed[t + s];
        __syncthreads();
    }
    if (t == 0) partials[blockIdx.x] = sRed[0];
}

__global__ __launch_bounds__(BTHREADS)
void chamfer_b(const float* __restrict__ partials,
               const float* __restrict__ blockMins,
               float* __restrict__ out) {
    __shared__ float sM[BTHREADS];
    __shared__ float sRed[BTHREADS];
    const int t = threadIdx.x;

    // t = b*512 + h*256 + c : thread mins its (batch, chunk-half, center) slice
    const int c = t & 255;
    const int h = (t >> 8) & 1;
    const int b = t >> 9;
    const float* src = blockMins + ((size_t)b * CHUNKS + h * (CHUNKS / 2)) * K + c;
    float m = 1e30f;
    #pragma unroll 5
    for (int j = 0; j < CHUNKS / 2; ++j)   // 75 coalesced rounds, independent loads
        m = fminf(m, src[(size_t)j * K]);
    sM[t] = m;
    __syncthreads();

    // combine halves, add dist2 partials, one fixed-tree sum (deterministic)
    float contrib = 0.0f;
    if (t < 512) {
        const int bb = t >> 8, cc = t & 255;
        contrib = fminf(sM[bb * 512 + cc], sM[bb * 512 + 256 + cc]);
    }
    if (t < NBA) contrib += partials[t];
    sRed[t] = contrib;
    __syncthreads();
    for (int s = BTHREADS / 2; s > 0; s >>= 1) {
        if (t < s) sRed[t] += sRed[t + s];
        __syncthreads();
    }
    if (t == 0) out[0] = 0.5f * sRed[0];   // mean over B=2
}

extern "C" void kernel_launch(void* const* d_in, const int* in_sizes, int n_in,
                              void* d_out, int out_size, void* d_ws, size_t ws_size,
                              hipStream_t stream) {
    const float* target = (const float*)d_in[0];   // [2,1,240,320] fp32
    const float* edges  = (const float*)d_in[1];   // [2,257] fp32
    float* out = (float*)d_out;

    float* partials  = (float*)d_ws;                       // NBA floats
    float* blockMins = (float*)((char*)d_ws + 2048);       // 2*CHUNKS*K floats

    chamfer_a<<<NBA, THREADS, 0, stream>>>(target, edges, partials, blockMins);
    chamfer_b<<<1, BTHREADS, 0, stream>>>(partials, blockMins, out);
}

// Round 5
// 14.584 us; speedup vs baseline: 2.8938x; 2.2296x over previous
//
#include <hip/hip_runtime.h>

#define K        256
#define NEDGE    257
#define NPTS     76800            // 240*320
#define THREADS  256
#define R1B      256              // role-1 blocks: 128 per batch, 2 centers each
#define R2CH     300              // role-2 chunks per batch (256 pts each)
#define R2B      (2 * R2CH)       // 600
#define NBLOCKS  (R1B + R2B)      // 856

// ws layout (no init needed — all written before read, every call):
//   float centerMin[2*K]   @ byte 0     (role-1 output: per-center min d^2)
//   float partials[R2B]    @ byte 2048  (role-2 output: per-chunk sum of per-point mins)

__global__ __launch_bounds__(THREADS)
void chamfer_a(const float* __restrict__ target,
               const float* __restrict__ edges,
               float* __restrict__ centerMin,
               float* __restrict__ partials) {
    const int t = threadIdx.x;

    if (blockIdx.x < R1B) {
        // ---- role 1: one block owns 2 centers, scans ALL points of its batch ----
        const int b  = blockIdx.x >> 7;          // 128 blocks per batch
        const int c0 = 2 * (blockIdx.x & 127);
        const float* e = edges + b * NEDGE;
        const float cA = 0.5f * (e[c0]     + e[c0 + 1]);
        const float cB = 0.5f * (e[c0 + 1] + e[c0 + 2]);

        const float4* p4 = (const float4*)(target + (size_t)b * NPTS);
        float a0 = 1e30f, a1 = 1e30f, b0 = 1e30f, b1 = 1e30f;
        #pragma unroll 5
        for (int i = 0; i < NPTS / 4 / THREADS; ++i) {   // 75 iters, coalesced float4
            const float4 p = p4[(size_t)i * THREADS + t];
            float x;
            x = p.x - cA; a0 = fminf(a0, x * x);
            x = p.y - cA; a1 = fminf(a1, x * x);
            x = p.z - cA; a0 = fminf(a0, x * x);
            x = p.w - cA; a1 = fminf(a1, x * x);
            x = p.x - cB; b0 = fminf(b0, x * x);
            x = p.y - cB; b1 = fminf(b1, x * x);
            x = p.z - cB; b0 = fminf(b0, x * x);
            x = p.w - cB; b1 = fminf(b1, x * x);
        }
        __shared__ float sA[THREADS];
        __shared__ float sB[THREADS];
        sA[t] = fminf(a0, a1);
        sB[t] = fminf(b0, b1);
        __syncthreads();
        for (int s = THREADS / 2; s > 0; s >>= 1) {
            if (t < s) {
                sA[t] = fminf(sA[t], sA[t + s]);
                sB[t] = fminf(sB[t], sB[t + s]);
            }
            __syncthreads();
        }
        if (t == 0) {
            centerMin[b * K + c0]     = sA[0];
            centerMin[b * K + c0 + 1] = sB[0];
        }
    } else {
        // ---- role 2: each thread's point vs all 256 centers (R1-proven) ----
        const int blk2  = blockIdx.x - R1B;
        const int b     = blk2 / R2CH;
        const int chunk = blk2 % R2CH;
        __shared__ float sC[K];
        __shared__ float sRed[THREADS];
        const float* e = edges + b * NEDGE;
        sC[t] = 0.5f * (e[t] + e[t + 1]);
        const float d = target[(size_t)b * NPTS + (size_t)chunk * THREADS + t];
        __syncthreads();

        float m0 = 1e30f, m1 = 1e30f, m2 = 1e30f, m3 = 1e30f;
        const float4* c4 = (const float4*)sC;    // uniform addr -> LDS broadcast
        #pragma unroll 16
        for (int i = 0; i < K / 4; ++i) {
            const float4 c = c4[i];
            float x;
            x = d - c.x; m0 = fminf(m0, x * x);
            x = d - c.y; m1 = fminf(m1, x * x);
            x = d - c.z; m2 = fminf(m2, x * x);
            x = d - c.w; m3 = fminf(m3, x * x);
        }
        sRed[t] = fminf(fminf(m0, m1), fminf(m2, m3));   // this point's min
        __syncthreads();
        for (int s = THREADS / 2; s > 0; s >>= 1) {      // fixed-tree SUM
            if (t < s) sRed[t] += sRed[t + s];
            __syncthreads();
        }
        if (t == 0) partials[blk2] = sRed[0];
    }
}

__global__ __launch_bounds__(THREADS)
void chamfer_b(const float* __restrict__ centerMin,
               const float* __restrict__ partials,
               float* __restrict__ out) {
    __shared__ float sRed[THREADS];
    const int t = threadIdx.x;
    float s = centerMin[t] + centerMin[t + THREADS];     // 512 center mins
    for (int i = t; i < R2B; i += THREADS) s += partials[i];  // fixed assignment
    sRed[t] = s;
    __syncthreads();
    for (int st = THREADS / 2; st > 0; st >>= 1) {
        if (t < st) sRed[t] += sRed[t + st];
        __syncthreads();
    }
    if (t == 0) out[0] = 0.5f * sRed[0];                 // mean over B=2
}

extern "C" void kernel_launch(void* const* d_in, const int* in_sizes, int n_in,
                              void* d_out, int out_size, void* d_ws, size_t ws_size,
                              hipStream_t stream) {
    const float* target = (const float*)d_in[0];   // [2,1,240,320] fp32
    const float* edges  = (const float*)d_in[1];   // [2,257] fp32
    float* out = (float*)d_out;

    float* centerMin = (float*)d_ws;                      // 512 floats
    float* partials  = (float*)((char*)d_ws + 2048);      // 600 floats

    chamfer_a<<<NBLOCKS, THREADS, 0, stream>>>(target, edges, centerMin, partials);
    chamfer_b<<<1, THREADS, 0, stream>>>(centerMin, partials, out);
}